// Round 1
// baseline (183.578 us; speedup 1.0000x reference)
//
#include <hip/hip_runtime.h>
#include <math.h>

// ---------------------------------------------------------------------------
// Setup kernel (1 wave): compute scale = kappa/||mu_unnorm|| and logC.
// All scalar math in double; the 64-term log-Bessel series uses an online
// logsumexp so no per-thread array is needed.
// ---------------------------------------------------------------------------
__global__ void vmf_setup_kernel(const float* __restrict__ mu_unnorm,
                                 const float* __restrict__ logkappa,
                                 float* __restrict__ params /* [0]=scale [1]=logC */) {
    const int lane = threadIdx.x;  // 64 threads, 1 wave
    // sum of squares over 512 elements: 8 per lane as two float4
    const float4* m4 = reinterpret_cast<const float4*>(mu_unnorm);
    float4 a = m4[lane];
    float4 b = m4[lane + 64];
    float ss = a.x * a.x + a.y * a.y + a.z * a.z + a.w * a.w
             + b.x * b.x + b.y * b.y + b.z * b.z + b.w * b.w;
    #pragma unroll
    for (int off = 1; off < 64; off <<= 1)
        ss += __shfl_xor(ss, off, 64);

    if (lane == 0) {
        const double dD = 512.0;
        const double s  = 0.5 * dD - 1.0;              // 255
        double norm = sqrt((double)ss);
        if (norm < 1e-12) norm = 1e-12;                // jnp.clip(norm, EPS)
        double kappa = exp((double)logkappa[0]) + 1e-6;
        double lhk = log(0.5 * kappa);

        // log I_s(kappa) = s*lhk + logsumexp_m( 2m*lhk - lgamma(m+1) - lgamma(m+s+1) )
        double run_max = -1e300, run_sum = 0.0;
        for (int m = 0; m < 64; ++m) {
            double t = 2.0 * (double)m * lhk
                     - lgamma((double)m + 1.0)
                     - lgamma((double)m + s + 1.0);
            if (t > run_max) {
                run_sum = run_sum * exp(run_max - t) + 1.0;
                run_max = t;
            } else {
                run_sum += exp(t - run_max);
            }
        }
        double logI = s * lhk + run_max + log(run_sum);

        const double NHLOG2PI = -0.9189385332046727417803297364056;  // -0.5*ln(2*pi)
        double logC = dD * NHLOG2PI + s * log(kappa) - logI;

        params[0] = (float)(kappa / norm);  // scale folds normalization into kappa
        params[1] = (float)logC;
    }
}

// ---------------------------------------------------------------------------
// Main kernel: one wave per row of x (D=512). Each lane: 2x float4 loads
// (coalesced, 16B/lane), 8 FMAs vs mu held in registers, shfl_xor reduce.
// Grid-stride over rows.
// ---------------------------------------------------------------------------
__global__ void __launch_bounds__(256)
vmf_main_kernel(const float* __restrict__ x,
                const float* __restrict__ mu,
                const float* __restrict__ params,
                float* __restrict__ out,
                int nrows) {
    const int lane  = threadIdx.x & 63;
    const int wid   = (blockIdx.x * (blockDim.x >> 6)) + (threadIdx.x >> 6);
    const int nwave = gridDim.x * (blockDim.x >> 6);

    const float scale = params[0];
    const float logC  = params[1];

    // mu (unnormalized) lives in registers across all rows this wave handles
    const float4* m4 = reinterpret_cast<const float4*>(mu);
    const float4 ma = m4[lane];
    const float4 mb = m4[lane + 64];

    for (int row = wid; row < nrows; row += nwave) {
        const float4* x4 = reinterpret_cast<const float4*>(x + (size_t)row * 512);
        float4 xa = x4[lane];
        float4 xb = x4[lane + 64];
        float dot = xa.x * ma.x + xa.y * ma.y + xa.z * ma.z + xa.w * ma.w
                  + xb.x * mb.x + xb.y * mb.y + xb.z * mb.z + xb.w * mb.w;
        #pragma unroll
        for (int off = 1; off < 64; off <<= 1)
            dot += __shfl_xor(dot, off, 64);
        if (lane == 0) out[row] = scale * dot + logC;
    }
}

extern "C" void kernel_launch(void* const* d_in, const int* in_sizes, int n_in,
                              void* d_out, int out_size, void* d_ws, size_t ws_size,
                              hipStream_t stream) {
    const float* x         = (const float*)d_in[0];
    const float* mu_unnorm = (const float*)d_in[1];
    const float* logkappa  = (const float*)d_in[2];
    float* out = (float*)d_out;
    float* params = (float*)d_ws;  // 2 floats of scratch

    const int D = 512;
    const int nrows = in_sizes[0] / D;  // 262144

    vmf_setup_kernel<<<1, 64, 0, stream>>>(mu_unnorm, logkappa, params);

    const int threads = 256;             // 4 waves/block
    const int blocks  = 2048;            // 8 blocks/CU, grid-stride covers all rows
    vmf_main_kernel<<<blocks, threads, 0, stream>>>(x, mu_unnorm, params, out, nrows);
}

// Round 2
// 100.115 us; speedup vs baseline: 1.8337x; 1.8337x over previous
//
#include <hip/hip_runtime.h>
#include <math.h>

// ---------------------------------------------------------------------------
// Setup kernel (1 wave): scale = kappa/||mu_unnorm||, logC.
// The 64-term log-Bessel series is parallelized: lane m computes term m
// (2 lgammas run concurrently across lanes), then shfl-based logsumexp.
// ---------------------------------------------------------------------------
__global__ void vmf_setup_kernel(const float* __restrict__ mu_unnorm,
                                 const float* __restrict__ logkappa,
                                 float* __restrict__ params, /* [0]=scale [1]=logC */
                                 int D) {
    const int lane = threadIdx.x;  // 64 threads, 1 wave

    // ||mu||^2 over D=512 elements: 8 per lane as two float4
    const float4* m4 = reinterpret_cast<const float4*>(mu_unnorm);
    float4 a = m4[lane];
    float4 b = m4[lane + 64];
    float ss = a.x * a.x + a.y * a.y + a.z * a.z + a.w * a.w
             + b.x * b.x + b.y * b.y + b.z * b.z + b.w * b.w;
    #pragma unroll
    for (int off = 1; off < 64; off <<= 1)
        ss += __shfl_xor(ss, off, 64);

    const double dD = (double)D;
    const double s  = 0.5 * dD - 1.0;
    double kappa = exp((double)logkappa[0]) + 1e-6;
    double lhk   = log(0.5 * kappa);

    // term_m = 2m*lhk - lgamma(m+1) - lgamma(m+s+1), one term per lane (N_TERMS=64)
    double m = (double)lane;
    double t = 2.0 * m * lhk - lgamma(m + 1.0) - lgamma(m + s + 1.0);

    // logsumexp across the wave
    double tmax = t;
    #pragma unroll
    for (int off = 1; off < 64; off <<= 1) {
        double o = __shfl_xor(tmax, off, 64);
        tmax = fmax(tmax, o);
    }
    double e = exp(t - tmax);
    #pragma unroll
    for (int off = 1; off < 64; off <<= 1)
        e += __shfl_xor(e, off, 64);

    if (lane == 0) {
        double logI = s * lhk + tmax + log(e);
        double norm = sqrt((double)ss);
        if (norm < 1e-12) norm = 1e-12;  // jnp.clip(norm, EPS)
        const double NHLOG2PI = -0.9189385332046727417803297364056;  // -0.5*ln(2*pi)
        double logC = dD * NHLOG2PI + s * log(kappa) - logI;
        params[0] = (float)(kappa / norm);  // fold normalization into kappa
        params[1] = (float)logC;
    }
}

// ---------------------------------------------------------------------------
// Main kernel: one wave per 4 rows of x (D=512). Per iteration: 8 coalesced
// global_load_dwordx4 in flight (8 KB/wave), 4 independent shuffle-reduce
// chains interleaved, lane 0 stores a float4 of 4 consecutive outputs.
// ---------------------------------------------------------------------------
__global__ void __launch_bounds__(256)
vmf_main_kernel(const float* __restrict__ x,
                const float* __restrict__ mu,
                const float* __restrict__ params,
                float* __restrict__ out,
                int nrows) {
    const int lane  = threadIdx.x & 63;
    const int wid   = (blockIdx.x * (blockDim.x >> 6)) + (threadIdx.x >> 6);
    const int nwave = gridDim.x * (blockDim.x >> 6);

    const float scale = params[0];
    const float logC  = params[1];

    // mu (unnormalized) in registers, reused across all rows this wave handles
    const float4* m4 = reinterpret_cast<const float4*>(mu);
    const float4 ma = m4[lane];
    const float4 mb = m4[lane + 64];

    int row = wid * 4;
    const int rstep = nwave * 4;

    for (; row + 3 < nrows; row += rstep) {
        const float4* x0 = reinterpret_cast<const float4*>(x + (size_t)(row + 0) * 512);
        const float4* x1 = reinterpret_cast<const float4*>(x + (size_t)(row + 1) * 512);
        const float4* x2 = reinterpret_cast<const float4*>(x + (size_t)(row + 2) * 512);
        const float4* x3 = reinterpret_cast<const float4*>(x + (size_t)(row + 3) * 512);
        float4 a0 = x0[lane], b0 = x0[lane + 64];
        float4 a1 = x1[lane], b1 = x1[lane + 64];
        float4 a2 = x2[lane], b2 = x2[lane + 64];
        float4 a3 = x3[lane], b3 = x3[lane + 64];

        float d0 = a0.x * ma.x + a0.y * ma.y + a0.z * ma.z + a0.w * ma.w
                 + b0.x * mb.x + b0.y * mb.y + b0.z * mb.z + b0.w * mb.w;
        float d1 = a1.x * ma.x + a1.y * ma.y + a1.z * ma.z + a1.w * ma.w
                 + b1.x * mb.x + b1.y * mb.y + b1.z * mb.z + b1.w * mb.w;
        float d2 = a2.x * ma.x + a2.y * ma.y + a2.z * ma.z + a2.w * ma.w
                 + b2.x * mb.x + b2.y * mb.y + b2.z * mb.z + b2.w * mb.w;
        float d3 = a3.x * ma.x + a3.y * ma.y + a3.z * ma.z + a3.w * ma.w
                 + b3.x * mb.x + b3.y * mb.y + b3.z * mb.z + b3.w * mb.w;

        // 4 independent butterfly chains, interleaved per step
        #pragma unroll
        for (int off = 1; off < 64; off <<= 1) {
            d0 += __shfl_xor(d0, off, 64);
            d1 += __shfl_xor(d1, off, 64);
            d2 += __shfl_xor(d2, off, 64);
            d3 += __shfl_xor(d3, off, 64);
        }

        if (lane == 0) {
            float4 o = make_float4(scale * d0 + logC, scale * d1 + logC,
                                   scale * d2 + logC, scale * d3 + logC);
            *reinterpret_cast<float4*>(out + row) = o;
        }
    }
    // tail (not hit for 262144 rows, kept for generality)
    for (; row < nrows; ++row) {
        const float4* x4 = reinterpret_cast<const float4*>(x + (size_t)row * 512);
        float4 xa = x4[lane], xb = x4[lane + 64];
        float dot = xa.x * ma.x + xa.y * ma.y + xa.z * ma.z + xa.w * ma.w
                  + xb.x * mb.x + xb.y * mb.y + xb.z * mb.z + xb.w * mb.w;
        #pragma unroll
        for (int off = 1; off < 64; off <<= 1)
            dot += __shfl_xor(dot, off, 64);
        if (lane == 0) out[row] = scale * dot + logC;
    }
}

extern "C" void kernel_launch(void* const* d_in, const int* in_sizes, int n_in,
                              void* d_out, int out_size, void* d_ws, size_t ws_size,
                              hipStream_t stream) {
    const float* x         = (const float*)d_in[0];
    const float* mu_unnorm = (const float*)d_in[1];
    const float* logkappa  = (const float*)d_in[2];
    float* out = (float*)d_out;
    float* params = (float*)d_ws;  // 2 floats of scratch

    const int D = 512;
    const int nrows = in_sizes[0] / D;  // 262144

    vmf_setup_kernel<<<1, 64, 0, stream>>>(mu_unnorm, logkappa, params, D);

    const int threads = 256;   // 4 waves/block
    const int blocks  = 2048;  // 8192 waves; 4 rows/wave/iter -> 8 iters
    vmf_main_kernel<<<blocks, threads, 0, stream>>>(x, mu_unnorm, params, out, nrows);
}

// Round 4
// 84.476 us; speedup vs baseline: 2.1731x; 1.1851x over previous
//
#include <hip/hip_runtime.h>
#include <math.h>

typedef float f32x4 __attribute__((ext_vector_type(4)));

// ---------------------------------------------------------------------------
// Fused vMF log-density kernel.
//   out[n] = scale * (x[n] . mu_unnorm) + logC,   scale = kappa/||mu_unnorm||
// Single kernel: each wave redundantly computes {scale, logC} (lane m owns
// Bessel term m; the f64 lgammas overlap the first tile's HBM latency), then
// streams 8 rows per iteration with 16 KB of nontemporal loads in flight and
// the next tile's loads issued before the current shuffle-reduce.
// ---------------------------------------------------------------------------
__global__ void __launch_bounds__(256)
vmf_fused_kernel(const float* __restrict__ x,
                 const float* __restrict__ mu,
                 const float* __restrict__ logkappa,
                 float* __restrict__ out,
                 int nrows, int D) {
    const int lane  = threadIdx.x & 63;
    const int wid   = (blockIdx.x * (blockDim.x >> 6)) + (threadIdx.x >> 6);
    const int nwave = gridDim.x * (blockDim.x >> 6);

    // mu (unnormalized) in registers, reused for all rows
    const f32x4* m4 = reinterpret_cast<const f32x4*>(mu);
    const f32x4 ma = m4[lane];
    const f32x4 mb = m4[lane + 64];

    // ---- prologue: issue first tile's 16 loads (no dependence on params) ----
    int row = wid * 8;
    const int rstep = nwave * 8;
    f32x4 xa[8], xb[8];
    bool have = (row + 7 < nrows);
    if (have) {
        #pragma unroll
        for (int r = 0; r < 8; ++r) {
            const f32x4* xp = reinterpret_cast<const f32x4*>(x + (size_t)(row + r) * D);
            xa[r] = __builtin_nontemporal_load(&xp[lane]);
            xb[r] = __builtin_nontemporal_load(&xp[lane + 64]);
        }
    }

    // ---- params (f64) — hides under the outstanding prologue loads ----
    float ss = ma.x * ma.x + ma.y * ma.y + ma.z * ma.z + ma.w * ma.w
             + mb.x * mb.x + mb.y * mb.y + mb.z * mb.z + mb.w * mb.w;
    #pragma unroll
    for (int off = 1; off < 64; off <<= 1)
        ss += __shfl_xor(ss, off, 64);

    const double dD = (double)D;
    const double s  = 0.5 * dD - 1.0;
    const double kappa = exp((double)logkappa[0]) + 1e-6;
    const double lhk   = log(0.5 * kappa);

    // term_m = 2m*lhk - lgamma(m+1) - lgamma(m+s+1); lane m owns term m (N_TERMS=64)
    double m = (double)lane;
    double t = 2.0 * m * lhk - lgamma(m + 1.0) - lgamma(m + s + 1.0);
    double tmax = t;
    #pragma unroll
    for (int off = 1; off < 64; off <<= 1)
        tmax = fmax(tmax, __shfl_xor(tmax, off, 64));
    double e = exp(t - tmax);
    #pragma unroll
    for (int off = 1; off < 64; off <<= 1)
        e += __shfl_xor(e, off, 64);
    double logI = s * lhk + tmax + log(e);

    double norm = sqrt((double)ss);
    if (norm < 1e-12) norm = 1e-12;  // jnp.clip(norm, EPS)
    const double NHLOG2PI = -0.9189385332046727417803297364056;  // -0.5*ln(2*pi)
    const float logC  = (float)(dD * NHLOG2PI + s * log(kappa) - logI);
    const float scale = (float)(kappa / norm);

    // ---- main loop: 8 rows / iteration ----
    while (have) {
        float d[8];
        #pragma unroll
        for (int r = 0; r < 8; ++r) {
            d[r] = xa[r].x * ma.x + xa[r].y * ma.y + xa[r].z * ma.z + xa[r].w * ma.w
                 + xb[r].x * mb.x + xb[r].y * mb.y + xb[r].z * mb.z + xb[r].w * mb.w;
        }
        const int crow = row;
        row += rstep;
        have = (row + 7 < nrows);
        if (have) {
            // issue next tile's loads BEFORE the reduce — they overlap the
            // 6-step shuffle chains below
            #pragma unroll
            for (int r = 0; r < 8; ++r) {
                const f32x4* xp = reinterpret_cast<const f32x4*>(x + (size_t)(row + r) * D);
                xa[r] = __builtin_nontemporal_load(&xp[lane]);
                xb[r] = __builtin_nontemporal_load(&xp[lane + 64]);
            }
        }
        // 8 independent butterfly chains, interleaved per step
        #pragma unroll
        for (int off = 1; off < 64; off <<= 1) {
            #pragma unroll
            for (int r = 0; r < 8; ++r)
                d[r] += __shfl_xor(d[r], off, 64);
        }
        if (lane == 0) {
            float4 o0 = make_float4(scale * d[0] + logC, scale * d[1] + logC,
                                    scale * d[2] + logC, scale * d[3] + logC);
            float4 o1 = make_float4(scale * d[4] + logC, scale * d[5] + logC,
                                    scale * d[6] + logC, scale * d[7] + logC);
            *reinterpret_cast<float4*>(out + crow)     = o0;
            *reinterpret_cast<float4*>(out + crow + 4) = o1;
        }
    }

    // ---- tail: remaining <8 rows (not hit for 262144, kept generic) ----
    row = wid * 8 + ((nrows / rstep) * rstep);  // recompute conservative start
    // simpler: handle any rows not covered by the 8-row loop
    for (int rr = (nrows & ~7) + wid; rr < nrows; rr += nwave) {
        const f32x4* xp = reinterpret_cast<const f32x4*>(x + (size_t)rr * D);
        f32x4 a = xp[lane], b = xp[lane + 64];
        float dot = a.x * ma.x + a.y * ma.y + a.z * ma.z + a.w * ma.w
                  + b.x * mb.x + b.y * mb.y + b.z * mb.z + b.w * mb.w;
        #pragma unroll
        for (int off = 1; off < 64; off <<= 1)
            dot += __shfl_xor(dot, off, 64);
        if (lane == 0) out[rr] = scale * dot + logC;
    }
}

extern "C" void kernel_launch(void* const* d_in, const int* in_sizes, int n_in,
                              void* d_out, int out_size, void* d_ws, size_t ws_size,
                              hipStream_t stream) {
    const float* x         = (const float*)d_in[0];
    const float* mu_unnorm = (const float*)d_in[1];
    const float* logkappa  = (const float*)d_in[2];
    float* out = (float*)d_out;

    const int D = 512;
    const int nrows = in_sizes[0] / D;  // 262144

    const int threads = 256;   // 4 waves/block
    const int blocks  = 2048;  // 8192 waves; 8 rows/wave/iter -> 4 grid-stride steps
    vmf_fused_kernel<<<blocks, threads, 0, stream>>>(x, mu_unnorm, logkappa, out, nrows, D);
}